// Round 5
// baseline (173.834 us; speedup 1.0000x reference)
//
#include <hip/hip_runtime.h>
#include <cstddef>

// ---------------------------------------------------------------------------
// JPEG blockwise 8x8 DCT + quantization.
//   image:          [16, 1, 1024, 1024] fp32
//   quality_factor: [16] fp32
//   out:            [16, 64, 128, 128] fp32, channel c = u*8+v
//
// R5: LDS-staged dense reads. R4 post-mortem: VALU cut was neutral => kernel
// (~28 us, 4.6 TB/s) is memory-side bound. Residual vs 6.3 TB/s ceiling
// blamed on 50%-density strided read instructions. Now: WG = 1 block-row,
// stage the 32KB input strip via fully-dense float4 loads -> LDS (block
// stride padded to 65 floats => every LDS phase <=2-way, free), then
// 2 threads/block compute the AAN DCT (duplicated - VALU is free) and
// store 4 u-rows each (lane-dense dword stores, 256B/instr).
// Roofline: 64 MB in + 64 MB out => ~20.3 us at 6.3 TB/s.
// ---------------------------------------------------------------------------

static constexpr double LUMQ[64] = {
    16, 11, 10, 16, 24, 40, 51, 61,
    12, 12, 14, 19, 26, 58, 60, 55,
    14, 13, 16, 24, 40, 57, 69, 56,
    14, 17, 22, 29, 51, 87, 80, 62,
    18, 22, 37, 56, 68, 109, 103, 77,
    24, 36, 55, 64, 81, 104, 113, 92,
    49, 64, 78, 87, 103, 121, 120, 101,
    72, 92, 95, 98, 112, 100, 103, 99,
};

// AAN per-coefficient scale: sqrt(2)*cos(k*pi/16), k=1..7; 1.0 for k=0.
static constexpr double AANS[8] = {
    1.0, 1.3870398453221475, 1.3065629648763766, 1.1758756024193588,
    1.0, 0.7856949583871022, 0.5411961001461970, 0.2758993792829430,
};

// Reference divides by Q = LUMQ/100; AAN raw 2D output is
// 8*aans[u]*aans[v] times the orthonormal DCT. Fold both (compile-time).
__device__ __host__ __forceinline__ constexpr float outScale(int u, int v) {
    return (float)(100.0 / (LUMQ[u * 8 + v] * 8.0 * AANS[u] * AANS[v]));
}

// AAN 8-point scaled forward DCT (jfdctflt.c flowgraph).
__device__ __forceinline__ void aan_dct8(float& x0, float& x1, float& x2,
                                         float& x3, float& x4, float& x5,
                                         float& x6, float& x7) {
    const float t0 = x0 + x7, t7 = x0 - x7;
    const float t1 = x1 + x6, t6 = x1 - x6;
    const float t2 = x2 + x5, t5 = x2 - x5;
    const float t3 = x3 + x4, t4 = x3 - x4;

    // Even part
    float t10 = t0 + t3;
    const float t13 = t0 - t3;
    const float t11 = t1 + t2;
    const float t12 = t1 - t2;
    x0 = t10 + t11;
    x4 = t10 - t11;
    const float z1 = (t12 + t13) * 0.70710678118654752f;
    x2 = t13 + z1;
    x6 = t13 - z1;

    // Odd part
    t10 = t4 + t5;
    const float u11 = t5 + t6;
    const float u12 = t6 + t7;
    const float z5 = (t10 - u12) * 0.38268343236508977f;
    const float z2 = 0.54119610014619698f * t10 + z5;
    const float z4 = 1.30656296487637653f * u12 + z5;
    const float z3 = u11 * 0.70710678118654752f;
    const float z11 = t7 + z3;
    const float z13 = t7 - z3;
    x5 = z13 + z2;
    x3 = z13 - z2;
    x1 = z11 + z4;
    x7 = z11 - z4;
}

// LDS: 128 blocks x (64 floats padded to 65) = 8320 floats = 33,280 B.
//  - stage-write (lane stride 65/2 + parity*4): every bank 2x per wave (free)
//  - compute-read b128 (lane stride 65): <=2-way per phase (free)
#define BLK_STRIDE 65

__global__ __launch_bounds__(256) void jpeg_dct_quant_kernel(
    const float* __restrict__ img,   // [16,1,1024,1024]
    const float* __restrict__ qfv,   // [16]
    float* __restrict__ out)         // [16,64,128,128]
{
    __shared__ float sm[BLK_STRIDE * 128];

    const int t   = threadIdx.x;
    const int row = blockIdx.x;         // 0..2047 = b*128 + i
    const int b   = row >> 7;
    const int i   = row & 127;

    // ---- Stage: 8 image rows x 4KB = 32KB, fully dense float4 loads. ----
    // iter p reads image row p; thread t covers floats 4t..4t+3 of that row,
    // i.e. block j = t>>1, m-offset = (t&1)*4.
    const float* strip = img + ((size_t)b << 20) + (size_t)(i * 8) * 1024;
    const int wj = t >> 1;
    const int wm = (t & 1) * 4;
    #pragma unroll
    for (int p = 0; p < 8; ++p) {
        const float4 r =
            *reinterpret_cast<const float4*>(strip + (size_t)p * 1024 + 4 * t);
        float* d = &sm[wj * BLK_STRIDE + p * 8 + wm];
        d[0] = r.x; d[1] = r.y; d[2] = r.z; d[3] = r.w;
    }

    __syncthreads();

    // ---- Compute: 2 threads per block, duplicated AAN (VALU is free). ----
    const int jb   = t & 127;           // block index
    const int half = t >> 7;            // wave-uniform: u 0..3 vs 4..7
    const float* blk = &sm[jb * BLK_STRIDE];

    float m[8][8];
    #pragma unroll
    for (int n = 0; n < 8; ++n) {
        const float4 lo = *reinterpret_cast<const float4*>(blk + n * 8);
        const float4 hi = *reinterpret_cast<const float4*>(blk + n * 8 + 4);
        m[n][0] = lo.x; m[n][1] = lo.y; m[n][2] = lo.z; m[n][3] = lo.w;
        m[n][4] = hi.x; m[n][5] = hi.y; m[n][6] = hi.z; m[n][7] = hi.w;
    }

    #pragma unroll
    for (int n = 0; n < 8; ++n)
        aan_dct8(m[n][0], m[n][1], m[n][2], m[n][3],
                 m[n][4], m[n][5], m[n][6], m[n][7]);
    #pragma unroll
    for (int v = 0; v < 8; ++v)
        aan_dct8(m[0][v], m[1][v], m[2][v], m[3][v],
                 m[4][v], m[5][v], m[6][v], m[7][v]);

    // -128 centering only affects the raw DC term: 128*64 = 8192.
    m[0][0] -= 8192.0f;

    const float qf = qfv[b];
    const float factor = (qf < 50.0f) ? (5000.0f / qf) : (200.0f - 2.0f * qf);
    const float invf = 1.0f / factor;

    // ---- Store this half's 4 u-rows: lane = consecutive jb => dense. ----
    float* dst = out + ((size_t)b << 20) + (size_t)i * 128 + jb;
    const int u0 = half * 4;
    #pragma unroll
    for (int uu = 0; uu < 4; ++uu) {
        const int u = u0 + uu;
        #pragma unroll
        for (int v = 0; v < 8; ++v)
            dst[(size_t)(u * 8 + v) * 16384] = m[u][v] * (invf * outScale(u, v));
    }
}

extern "C" void kernel_launch(void* const* d_in, const int* in_sizes, int n_in,
                              void* d_out, int out_size, void* d_ws, size_t ws_size,
                              hipStream_t stream) {
    const float* img = (const float*)d_in[0];   // 16*1024*1024 fp32
    const float* qfv = (const float*)d_in[1];   // 16 fp32
    float* out = (float*)d_out;                 // 16*64*128*128 fp32

    // 2048 block-rows (16 b x 128 i), one WG each; 2 threads per 8x8 block.
    jpeg_dct_quant_kernel<<<2048, 256, 0, stream>>>(img, qfv, out);
}

// Round 6
// 111.696 us; speedup vs baseline: 1.5563x; 1.5563x over previous
//
#include <hip/hip_runtime.h>
#include <cstddef>

// ---------------------------------------------------------------------------
// JPEG blockwise 8x8 DCT + quantization.
//   image:          [16, 1, 1024, 1024] fp32
//   quality_factor: [16] fp32
//   out:            [16, 64, 128, 128] fp32, channel c = u*8+v
//
// R6 = R4 restored (best measured: kernel ~28 us, dur_us 111.2).
// Post-mortems: R3 (2T-split + nt stores) and R5 (LDS-staged dense reads)
// both regressed 3x with ~3x WRITE_SIZE amplification; R4's strided float4
// reads are already clean at the HBM level (L1 merges the 50%-density
// companion pairs) and VALU is invisible (R2->R4 AAN cut was exactly
// neutral). Mixed 1:1 R/W stream ceiling ~= 0.8 * 6.3 TB/s = 5.0 TB/s
// => 128 MB / 5.0 ~= 25.5 us; R4 runs ~28 us (~90%).
// ---------------------------------------------------------------------------

static constexpr double LUMQ[64] = {
    16, 11, 10, 16, 24, 40, 51, 61,
    12, 12, 14, 19, 26, 58, 60, 55,
    14, 13, 16, 24, 40, 57, 69, 56,
    14, 17, 22, 29, 51, 87, 80, 62,
    18, 22, 37, 56, 68, 109, 103, 77,
    24, 36, 55, 64, 81, 104, 113, 92,
    49, 64, 78, 87, 103, 121, 120, 101,
    72, 92, 95, 98, 112, 100, 103, 99,
};

// AAN per-coefficient scale: sqrt(2)*cos(k*pi/16), k=1..7; 1.0 for k=0.
static constexpr double AANS[8] = {
    1.0, 1.3870398453221475, 1.3065629648763766, 1.1758756024193588,
    1.0, 0.7856949583871022, 0.5411961001461970, 0.2758993792829430,
};

// Reference divides by Q = LUMQ/100; AAN raw 2D output is
// 8*aans[u]*aans[v] times the orthonormal DCT. Fold both (compile-time).
__device__ __host__ __forceinline__ constexpr float outScale(int u, int v) {
    return (float)(100.0 / (LUMQ[u * 8 + v] * 8.0 * AANS[u] * AANS[v]));
}

// AAN 8-point scaled forward DCT (jfdctflt.c flowgraph).
// Output k is the true orthonormal DCT * sqrt(8) * aans[k].
__device__ __forceinline__ void aan_dct8(float& x0, float& x1, float& x2,
                                         float& x3, float& x4, float& x5,
                                         float& x6, float& x7) {
    const float t0 = x0 + x7, t7 = x0 - x7;
    const float t1 = x1 + x6, t6 = x1 - x6;
    const float t2 = x2 + x5, t5 = x2 - x5;
    const float t3 = x3 + x4, t4 = x3 - x4;

    // Even part
    float t10 = t0 + t3;
    const float t13 = t0 - t3;
    const float t11 = t1 + t2;
    const float t12 = t1 - t2;
    x0 = t10 + t11;
    x4 = t10 - t11;
    const float z1 = (t12 + t13) * 0.70710678118654752f;
    x2 = t13 + z1;
    x6 = t13 - z1;

    // Odd part
    t10 = t4 + t5;
    const float u11 = t5 + t6;
    const float u12 = t6 + t7;
    const float z5 = (t10 - u12) * 0.38268343236508977f;
    const float z2 = 0.54119610014619698f * t10 + z5;
    const float z4 = 1.30656296487637653f * u12 + z5;
    const float z3 = u11 * 0.70710678118654752f;
    const float z11 = t7 + z3;
    const float z13 = t7 - z3;
    x5 = z13 + z2;
    x3 = z13 - z2;
    x1 = z11 + z4;
    x7 = z11 - z4;
}

__global__ __launch_bounds__(256) void jpeg_dct_quant_kernel(
    const float* __restrict__ img,   // [16,1,1024,1024]
    const float* __restrict__ qfv,   // [16]
    float* __restrict__ out)         // [16,64,128,128]
{
    const int bid = blockIdx.x * 256 + threadIdx.x;   // global 8x8-block id
    const int j = bid & 127;           // block col
    const int i = (bid >> 7) & 127;    // block row
    const int b = bid >> 14;           // batch

    const float* src = img + ((size_t)b << 20) + (size_t)(i * 8) * 1024 + j * 8;

    // Load the full 8x8 block first (MLP = 16 outstanding float4 loads).
    float m[8][8];
    #pragma unroll
    for (int n = 0; n < 8; ++n) {
        const float4 r0 = *reinterpret_cast<const float4*>(src + (size_t)n * 1024);
        const float4 r1 = *reinterpret_cast<const float4*>(src + (size_t)n * 1024 + 4);
        m[n][0] = r0.x; m[n][1] = r0.y; m[n][2] = r0.z; m[n][3] = r0.w;
        m[n][4] = r1.x; m[n][5] = r1.y; m[n][6] = r1.z; m[n][7] = r1.w;
    }

    // Row pass (along columns within each row).
    #pragma unroll
    for (int n = 0; n < 8; ++n)
        aan_dct8(m[n][0], m[n][1], m[n][2], m[n][3],
                 m[n][4], m[n][5], m[n][6], m[n][7]);

    // Column pass.
    #pragma unroll
    for (int v = 0; v < 8; ++v)
        aan_dct8(m[0][v], m[1][v], m[2][v], m[3][v],
                 m[4][v], m[5][v], m[6][v], m[7][v]);

    // -128 centering only affects the raw DC term: 128*64 = 8192.
    m[0][0] -= 8192.0f;

    const float qf = qfv[b];
    const float factor = (qf < 50.0f) ? (5000.0f / qf) : (200.0f - 2.0f * qf);
    const float invf = 1.0f / factor;

    // Stores: lane = consecutive j => each wave store instr is 256 B dense.
    float* dst = out + ((size_t)b << 20) + (size_t)i * 128 + j;
    #pragma unroll
    for (int u = 0; u < 8; ++u)
        #pragma unroll
        for (int v = 0; v < 8; ++v)
            dst[(size_t)(u * 8 + v) * 16384] = m[u][v] * (invf * outScale(u, v));
}

extern "C" void kernel_launch(void* const* d_in, const int* in_sizes, int n_in,
                              void* d_out, int out_size, void* d_ws, size_t ws_size,
                              hipStream_t stream) {
    const float* img = (const float*)d_in[0];   // 16*1024*1024 fp32
    const float* qfv = (const float*)d_in[1];   // 16 fp32
    float* out = (float*)d_out;                 // 16*64*128*128 fp32

    // 16*128*128 = 262144 blocks, one thread each; 256 threads/WG -> 1024 WGs.
    jpeg_dct_quant_kernel<<<1024, 256, 0, stream>>>(img, qfv, out);
}